// Round 21
// baseline (160.156 us; speedup 1.0000x reference)
//
#include <hip/hip_runtime.h>
#include <hip/hip_bf16.h>

#define NBATCH 16
#define NBR    8
#define CIN    3
#define HIN    224
#define WIN    224
#define COUT   64
#define OHH    112
#define OWW    112
#define PHH    56
#define PWW    56
#define CNT    (NBATCH*OHH*OWW)                  // 200704 per (b,co) channel

// padded x: per image [3 ci][230 h][232 w] bf16 (zeros baked in)
#define XCI  3
#define XH   230
#define XW   232
#define XIMG ((size_t)XCI*XH*XW)                 // 160080 elems per image
#define BROW 200                                 // wt row stride in ushorts (192 + 8 pad)
#define YHSLOT ((size_t)NBATCH*OHH*PWW*COUT)     // row-pooled elems per branch (6.42M)

typedef __bf16 bf16x8 __attribute__((ext_vector_type(8)));
typedef float  f32x4  __attribute__((ext_vector_type(4)));
typedef unsigned int uint4v __attribute__((ext_vector_type(4)));
typedef unsigned short ushort4v __attribute__((ext_vector_type(4)));

// ---------- wt[b][co][k'] bf16: k' = g*8+j, g=(ci*7+kh), j=kw (j=7 or g>=21 -> 0) ----------
__global__ __launch_bounds__(256)
void prep_w(const float* __restrict__ w, ushort* __restrict__ wt)
{
    int i = blockIdx.x*256 + threadIdx.x;
    if (i >= NBR*COUT*BROW) return;
    int k = i % BROW;
    int t = i / BROW;                       // b*64 + co
    float v = 0.f;
    if (k < 168) {
        int g = k >> 3, j = k & 7;
        if (j < 7) {
            int ci = g / 7, kh = g - 7*ci;
            v = w[(size_t)t*147 + ci*49 + kh*7 + j];
        }
    }
    __hip_bfloat16 h = __float2bfloat16(v);
    wt[i] = *reinterpret_cast<ushort*>(&h);
}

// ---------- padded bf16 x, FULL 3-plane surface; interior via 16B dwordx4 loads ----------
__global__ __launch_bounds__(256)
void prep_x(const float* __restrict__ x, ushort* __restrict__ xp)
{
    int bid   = blockIdx.x;
    int strip = bid % 23;
    int t2    = bid / 23;
    int ci    = t2 % 3;
    int img   = t2 / 3;
    ushort* dst = xp + (size_t)img*XIMG + (size_t)ci*XH*XW;
    const float* src = x + ((size_t)img*3 + ci)*HIN*WIN;

    for (int i = threadIdx.x; i < 10*58; i += 256) {
        int rr = i / 58;
        int g  = i - rr*58;
        int hh = strip*10 + rr;          // 0..229
        int c0 = g*4;
        int ih = hh - 3;
        ushort4v v;
        if ((unsigned)ih < (unsigned)HIN && c0 >= 4 && c0 <= 220) {
            // interior: one unaligned-16B (4B-aligned) vector load
            float f4[4];
            __builtin_memcpy(f4, src + ih*WIN + (c0 - 3), 16);
            #pragma unroll
            for (int j = 0; j < 4; ++j) {
                __hip_bfloat16 h = __float2bfloat16(f4[j]);
                v[j] = *reinterpret_cast<ushort*>(&h);
            }
        } else {
            #pragma unroll
            for (int j = 0; j < 4; ++j) {
                int iw = c0 + j - 3;
                float f = 0.f;
                if ((unsigned)ih < (unsigned)HIN && (unsigned)iw < (unsigned)WIN)
                    f = src[ih*WIN + iw];
                __hip_bfloat16 h = __float2bfloat16(f);
                v[j] = *reinterpret_cast<ushort*>(&h);
            }
        }
        *(ushort4v*)&dst[hh*XW + c0] = v;
    }
}

// ---------- MFMA conv + BN stats + horizontal 3x1 s2 pool, 7 ROWS PER WAVE ----------
// (unchanged from r20: 512 blocks = 2/CU, o~5.6 amortized over 56 tiles, ks=5 A-load
// only on q==0, k-groups>=21 zeroed in-register)
__global__ __launch_bounds__(256)
void conv_mfma(const ushort* __restrict__ xp, const ushort* __restrict__ wt,
               ushort* __restrict__ yh, float* __restrict__ stats)
{
    __shared__ ushort bt[COUT*BROW];     // 25.6 KB
    __shared__ float red[4][2][COUT];    // 2 KB

    int bloc = blockIdx.x / 64;
    int rem  = blockIdx.x % 64;
    int tid  = threadIdx.x;
    int wid  = tid >> 6;
    int lane = tid & 63;
    int l15  = lane & 15;
    int q    = lane >> 4;
    int base = rem*28;                   // block covers rows [base, base+28)
    int b    = bloc;

    {   // stage wt row-block into LDS (coalesced dword copy, once per block)
        const uint* s = (const uint*)(wt + (size_t)b*COUT*BROW);
        uint* d = (uint*)bt;
        for (int i = tid; i < COUT*BROW/2; i += 256) d[i] = s[i];
    }
    __syncthreads();

    int goff[6];
    bool ld5 = (q == 0);                 // ks=5: g=20+q; g>=21 has zero weights
    #pragma unroll
    for (int ks = 0; ks < 6; ++ks) {
        int g = ks*4 + q;
        int gc = (g > 20) ? 20 : g;      // clamp (unused lanes), stay in-plane
        int ci = gc / 7, kh = gc - 7*ci;
        goff[ks] = (ci*XH + kh) * (XW*2);
    }

    float ss[4] = {0.f,0.f,0.f,0.f}, sq[4] = {0.f,0.f,0.f,0.f};

    #pragma unroll 1
    for (int t = 0; t < 7; ++t) {
        int row = base + wid + 4*t;      // 0..1791
        int n   = row / OHH;
        int oh  = row % OHH;
        int img = n*NBR + b;

        const char* rowbase = (const char*)xp + (size_t)img*(XIMG*2)
                            + (size_t)(2*oh)*(XW*2) + (size_t)(4*l15) - 4;
        ushort* yrow = yh + (size_t)bloc*YHSLOT + (((size_t)n*OHH + oh)*PWW)*64;

        #pragma unroll 1
        for (int u = 0; u < 8; ++u) {
            const char* abase = rowbase + (size_t)(56*u);

            uint4v afr[6];
            #pragma unroll
            for (int ks = 0; ks < 5; ++ks)
                __builtin_memcpy(&afr[ks], abase + goff[ks], 16);
            afr[5] = (uint4v){0u,0u,0u,0u};
            if (ld5) __builtin_memcpy(&afr[5], abase + goff[5], 16);

            f32x4 acc[4];
            #pragma unroll
            for (int nt = 0; nt < 4; ++nt) acc[nt] = (f32x4){0.f,0.f,0.f,0.f};

            #pragma unroll
            for (int ks = 0; ks < 6; ++ks)
                #pragma unroll
                for (int nt = 0; nt < 4; ++nt) {
                    uint4v bf = *(const uint4v*)&bt[(nt*16 + l15)*BROW + ks*32 + q*8];
                    acc[nt] = __builtin_amdgcn_mfma_f32_16x16x32_bf16(
                        __builtin_bit_cast(bf16x8, afr[ks]),
                        __builtin_bit_cast(bf16x8, bf), acc[nt], 0, 0, 0);
                }

            #pragma unroll
            for (int nt = 0; nt < 4; ++nt) {
                float v0 = acc[nt][0], v1 = acc[nt][1], v2 = acc[nt][2], v3 = acc[nt][3];

                // stats: locals 1..14 (q0 skips r0; q3 skips r3)
                float a0 = (q == 0) ? 0.f : v0;
                float a3 = (q == 3) ? 0.f : v3;
                ss[nt] += a0 + v1 + v2 + a3;
                sq[nt] += a0*a0 + v1*v1 + v2*v2 + a3*a3;

                float nv0 = __shfl_down(v0, 16);              // (q+1)'s v0
                float v0e = (u == 0 && q == 0) ? -3e38f : v0; // pw=0 left pad = -inf
                float m0 = fmaxf(fmaxf(v0e, v1), v2);         // pw = 7u + 2q
                float m1 = fmaxf(fmaxf(v2, v3), nv0);         // pw = 7u + 2q+1 (q<3)

                int o0 = (7*u + 2*q)*64 + nt*16 + l15;
                __hip_bfloat16 h0 = __float2bfloat16(m0);
                yrow[o0] = *reinterpret_cast<ushort*>(&h0);
                if (q < 3) {
                    __hip_bfloat16 h1 = __float2bfloat16(m1);
                    yrow[o0 + 64] = *reinterpret_cast<ushort*>(&h1);
                }
            }
        }
    }

    // stats: reduce over q lanes, then waves, one atomic per co
    #pragma unroll
    for (int nt = 0; nt < 4; ++nt) {
        float s1 = ss[nt]; s1 += __shfl_xor(s1, 16); s1 += __shfl_xor(s1, 32);
        float q1 = sq[nt]; q1 += __shfl_xor(q1, 16); q1 += __shfl_xor(q1, 32);
        if (q == 0) {
            red[wid][0][nt*16 + l15] = s1;
            red[wid][1][nt*16 + l15] = q1;
        }
    }
    __syncthreads();
    if (tid < COUT) {
        float s1 = red[0][0][tid] + red[1][0][tid] + red[2][0][tid] + red[3][0][tid];
        float q1 = red[0][1][tid] + red[1][1][tid] + red[2][1][tid] + red[3][1][tid];
        atomicAdd(&stats[b*128 + tid*2 + 0], s1);
        atomicAdd(&stats[b*128 + tid*2 + 1], q1);
    }
}

// ---------- vertical 3-tap pool + BN-affine + ReLU; res[co][pw] LDS + float4 writes ----------
// block = (bloc, n, group of 8 ph); write phase emits 16B float4 stores into NCHW out.
__global__ __launch_bounds__(256)
void vpool(const ushort* __restrict__ yh, const float* __restrict__ stats,
           const float* __restrict__ gamma, const float* __restrict__ beta,
           float* __restrict__ out)
{
    int bid  = blockIdx.x;
    int bloc = bid / (NBATCH*(PHH/8));
    int r    = bid % (NBATCH*(PHH/8));
    int n    = r / (PHH/8);
    int phg  = r % (PHH/8);
    int b    = bloc;
    int tid  = threadIdx.x;

    __shared__ float res[COUT][60];          // 15.4 KB, 16B-aligned rows
    __shared__ float sscale[COUT], sshift[COUT];

    if (tid < COUT) {
        float mean = stats[b*128 + tid*2 + 0] * (1.f/CNT);
        float var  = stats[b*128 + tid*2 + 1] * (1.f/CNT) - mean*mean;
        float inv  = rsqrtf(var + 1e-5f);
        float sc   = gamma[b*COUT + tid]*inv;
        sscale[tid] = sc;
        sshift[tid] = beta[b*COUT + tid] - mean*sc;
    }
    __syncthreads();

    const ushort* base = yh + (size_t)bloc*YHSLOT + (size_t)n*OHH*PWW*64;
    int c8 = (tid & 7) * 8;      // co octet
    int pg = tid >> 3;           // 0..31

    #pragma unroll 1
    for (int pi = 0; pi < 8; ++pi) {
        int ph  = phg*8 + pi;
        int ihA = (2*ph-1 < 0) ? 0 : 2*ph-1;
        int ihC = (2*ph+1 > OHH-1) ? OHH-1 : 2*ph+1;
        const ushort* rA = base + (size_t)ihA*PWW*64;
        const ushort* rB = base + (size_t)(2*ph)*PWW*64;
        const ushort* rC = base + (size_t)ihC*PWW*64;

        #pragma unroll
        for (int t = 0; t < 2; ++t) {
            int pw = pg + 32*t;
            if (pw < PWW) {
                int o = pw*64 + c8;
                uint4v a  = *(const uint4v*)(rA + o);
                uint4v bb = *(const uint4v*)(rB + o);
                uint4v c  = *(const uint4v*)(rC + o);
                #pragma unroll
                for (int i = 0; i < 4; ++i) {
                    uint ua = a[i], ub = bb[i], uc = c[i];
                    float a0 = __builtin_bit_cast(float, ua << 16);
                    float a1 = __builtin_bit_cast(float, ua & 0xffff0000u);
                    float b0 = __builtin_bit_cast(float, ub << 16);
                    float b1 = __builtin_bit_cast(float, ub & 0xffff0000u);
                    float c0 = __builtin_bit_cast(float, uc << 16);
                    float c1 = __builtin_bit_cast(float, uc & 0xffff0000u);
                    float m0 = fmaxf(fmaxf(a0, b0), c0);
                    float m1 = fmaxf(fmaxf(a1, b1), c1);
                    int co0 = c8 + 2*i, co1 = co0 + 1;
                    res[co0][pw] = fmaxf(fmaf(m0, sscale[co0], sshift[co0]), 0.f);
                    res[co1][pw] = fmaxf(fmaf(m1, sscale[co1], sshift[co1]), 0.f);
                }
            }
        }
        __syncthreads();

        float* ob = out + (((size_t)n*NBR + b)*COUT)*(PHH*PWW) + (size_t)ph*PWW;
        for (int j = tid; j < COUT*14; j += 256) {
            int co = j / 14;
            int p4 = (j - co*14) * 4;
            f32x4 v = *(const f32x4*)&res[co][p4];
            *(f32x4*)&ob[(size_t)co*(PHH*PWW) + p4] = v;
        }
        __syncthreads();
    }
}

// ================= fallback path (tiny workspace) =================
__global__ __launch_bounds__(512)
void conv_bn_stats(const float* __restrict__ x, const float* __restrict__ w,
                   float* __restrict__ stats, int b)
{
    __shared__ float xs[CIN][7][232];
    int bid = blockIdx.x;
    int oh  = bid % OHH;
    int n   = bid / OHH;
    const float* xb = x + ((size_t)(n*NBR + b))*CIN*HIN*WIN;
    int ihb = oh*2 - 3;
    for (int idx = threadIdx.x; idx < CIN*7*230; idx += 512) {
        int ci = idx / (7*230);
        int rr = idx - ci*(7*230);
        int kh = rr / 230;
        int c  = rr - kh*230;
        int ih = ihb + kh, iw = c - 3;
        float v = 0.f;
        if ((unsigned)ih < (unsigned)HIN && (unsigned)iw < (unsigned)WIN)
            v = xb[(ci*HIN + ih)*WIN + iw];
        xs[ci][kh][c] = v;
    }
    __syncthreads();
    int wid  = __builtin_amdgcn_readfirstlane(threadIdx.x >> 6);
    int lane = threadIdx.x & 63;
    int co0  = wid * 8;
    const float* wb = w + ((size_t)b*COUT + co0)*147;
    float acc0[8], acc1[8];
    #pragma unroll
    for (int cc = 0; cc < 8; ++cc) { acc0[cc] = 0.f; acc1[cc] = 0.f; }
    int ow1 = lane + 64;
    for (int ci = 0; ci < CIN; ++ci)
        for (int kh = 0; kh < 7; ++kh) {
            float wr[8][7];
            #pragma unroll
            for (int cc = 0; cc < 8; ++cc)
                #pragma unroll
                for (int kw = 0; kw < 7; ++kw)
                    wr[cc][kw] = wb[cc*147 + ci*49 + kh*7 + kw];
            const float* xr = &xs[ci][kh][0];
            #pragma unroll
            for (int kw = 0; kw < 7; ++kw) {
                float xv0 = xr[lane*2 + kw];
                float xv1 = (ow1 < OWW) ? xr[ow1*2 + kw] : 0.f;
                #pragma unroll
                for (int cc = 0; cc < 8; ++cc) {
                    acc0[cc] = fmaf(xv0, wr[cc][kw], acc0[cc]);
                    acc1[cc] = fmaf(xv1, wr[cc][kw], acc1[cc]);
                }
            }
        }
    #pragma unroll
    for (int cc = 0; cc < 8; ++cc) {
        float s = acc0[cc] + acc1[cc];
        float qv = acc0[cc]*acc0[cc] + acc1[cc]*acc1[cc];
        #pragma unroll
        for (int off = 32; off; off >>= 1) {
            s  += __shfl_xor(s, off);
            qv += __shfl_xor(qv, off);
        }
        if (lane == 0) {
            atomicAdd(&stats[(co0+cc)*2 + 0], s);
            atomicAdd(&stats[(co0+cc)*2 + 1], qv);
        }
    }
}

__global__ __launch_bounds__(256)
void pool_recompute(const float* __restrict__ x, const float* __restrict__ w,
                    const float* __restrict__ stats, const float* __restrict__ gamma,
                    const float* __restrict__ beta, float* __restrict__ out, int b)
{
    int idx = blockIdx.x*256 + threadIdx.x;
    int pw = idx % PWW;
    int t  = idx / PWW;
    int ph = t % PHH; t /= PHH;
    int co = t % COUT;
    int n  = t / COUT;
    float mean = stats[co*2 + 0] * (1.f/CNT);
    float var  = stats[co*2 + 1] * (1.f/CNT) - mean*mean;
    float inv  = rsqrtf(var + 1e-5f);
    float scale = gamma[co]*inv;
    float shift = beta[co] - mean*scale;
    const float* xb = x + ((size_t)(n*NBR + b))*CIN*HIN*WIN;
    const float* wb = w + ((size_t)b*COUT + co)*147;
    float mx = -1e30f, mn = 1e30f;
    for (int dh = 0; dh < 3; ++dh) {
        int oh = 2*ph - 1 + dh;
        if ((unsigned)oh >= (unsigned)OHH) continue;
        for (int dw = 0; dw < 3; ++dw) {
            int ow = 2*pw - 1 + dw;
            if ((unsigned)ow >= (unsigned)OWW) continue;
            float a = 0.f;
            for (int ci = 0; ci < CIN; ++ci)
                for (int kh = 0; kh < 7; ++kh) {
                    int ih = oh*2 - 3 + kh;
                    if ((unsigned)ih >= (unsigned)HIN) continue;
                    for (int kw = 0; kw < 7; ++kw) {
                        int iw = ow*2 - 3 + kw;
                        if ((unsigned)iw >= (unsigned)WIN) continue;
                        a = fmaf(xb[(ci*HIN + ih)*WIN + iw], wb[ci*49 + kh*7 + kw], a);
                    }
                }
            mx = fmaxf(mx, a);
            mn = fminf(mn, a);
        }
    }
    float v = (scale >= 0.f) ? mx : mn;
    out[(((size_t)n*NBR + b)*COUT + co)*(PHH*PWW) + (size_t)ph*PWW + pw] =
        fmaxf(fmaf(v, scale, shift), 0.f);
}

extern "C" void kernel_launch(void* const* d_in, const int* in_sizes, int n_in,
                              void* d_out, int out_size, void* d_ws, size_t ws_size,
                              hipStream_t stream) {
    const float* x     = (const float*)d_in[0];
    const float* w     = (const float*)d_in[1];
    const float* gamma = (const float*)d_in[2];
    const float* beta  = (const float*)d_in[3];
    float* out = (float*)d_out;

    // ws: [0,4K) stats; [4K,~414K) wt; [512K, +41MB) xpad; then yh (102.8 MB)
    float*  stats = (float*)d_ws;
    ushort* wt    = (ushort*)((char*)d_ws + 4096);
    ushort* xp    = (ushort*)((char*)d_ws + 524288);
    const size_t xpend = 524288 + (size_t)128*XIMG*2;     // ~41.5 MB
    ushort* yh = (ushort*)((char*)d_ws + xpend);
    const size_t need = xpend + (size_t)NBR*YHSLOT*2;     // ~144 MB

    hipMemsetAsync(d_ws, 0, NBR*128*sizeof(float), stream);   // stats only

    if (ws_size >= need) {
        prep_w<<<(NBR*COUT*BROW + 255)/256, 256, 0, stream>>>(w, wt);
        prep_x<<<128*3*23, 256, 0, stream>>>(x, xp);
        conv_mfma<<<NBR*64, 256, 0, stream>>>(xp, wt, yh, stats);
        vpool<<<NBR*NBATCH*(PHH/8), 256, 0, stream>>>(yh, stats, gamma, beta, out);
    } else {
        for (int b = 0; b < NBR; ++b) {
            float* statsB = stats + b*128;
            conv_bn_stats<<<NBATCH*OHH, 512, 0, stream>>>(x, w, statsB, b);
            pool_recompute<<<NBATCH*COUT*PHH*PWW/256, 256, 0, stream>>>(
                x, w, statsB, gamma + b*COUT, beta + b*COUT, out, b);
        }
    }
}

// Round 22
// 149.621 us; speedup vs baseline: 1.0704x; 1.0704x over previous
//
#include <hip/hip_runtime.h>
#include <hip/hip_bf16.h>

#define NBATCH 16
#define NBR    8
#define CIN    3
#define HIN    224
#define WIN    224
#define COUT   64
#define OHH    112
#define OWW    112
#define PHH    56
#define PWW    56
#define CNT    (NBATCH*OHH*OWW)                  // 200704 per (b,co) channel

// padded x: per image [3 ci][230 h][232 w] bf16 (zeros baked in)
#define XCI  3
#define XH   230
#define XW   232
#define XIMG ((size_t)XCI*XH*XW)                 // 160080 elems per image
#define BROW 200                                 // wt row stride in ushorts (192 + 8 pad)
#define YHSLOT ((size_t)NBATCH*OHH*PWW*COUT)     // row-pooled elems per branch (6.42M)

typedef __bf16 bf16x8 __attribute__((ext_vector_type(8)));
typedef float  f32x4  __attribute__((ext_vector_type(4)));
typedef unsigned int uint4v __attribute__((ext_vector_type(4)));
typedef unsigned short ushort4v __attribute__((ext_vector_type(4)));

// ---------- wt[b][co][k'] bf16: k' = g*8+j, g=(ci*7+kh), j=kw (j=7 or g>=21 -> 0) ----------
__global__ __launch_bounds__(256)
void prep_w(const float* __restrict__ w, ushort* __restrict__ wt)
{
    int i = blockIdx.x*256 + threadIdx.x;
    if (i >= NBR*COUT*BROW) return;
    int k = i % BROW;
    int t = i / BROW;                       // b*64 + co
    float v = 0.f;
    if (k < 168) {
        int g = k >> 3, j = k & 7;
        if (j < 7) {
            int ci = g / 7, kh = g - 7*ci;
            v = w[(size_t)t*147 + ci*49 + kh*7 + j];
        }
    }
    __hip_bfloat16 h = __float2bfloat16(v);
    wt[i] = *reinterpret_cast<ushort*>(&h);
}

// ---------- padded bf16 x, FULL 3-plane surface (zeros baked in; no memset) ----------
__global__ __launch_bounds__(256)
void prep_x(const float* __restrict__ x, ushort* __restrict__ xp)
{
    int bid   = blockIdx.x;
    int strip = bid % 23;
    int t2    = bid / 23;
    int ci    = t2 % 3;
    int img   = t2 / 3;
    ushort* dst = xp + (size_t)img*XIMG + (size_t)ci*XH*XW;
    const float* src = x + ((size_t)img*3 + ci)*HIN*WIN;

    for (int i = threadIdx.x; i < 10*58; i += 256) {
        int rr = i / 58;
        int g  = i - rr*58;
        int hh = strip*10 + rr;          // 0..229
        int c0 = g*4;
        int ih = hh - 3;
        ushort4v v;
        #pragma unroll
        for (int j = 0; j < 4; ++j) {
            int iw = c0 + j - 3;
            float f = 0.f;
            if ((unsigned)ih < (unsigned)HIN && (unsigned)iw < (unsigned)WIN)
                f = src[ih*WIN + iw];
            __hip_bfloat16 h = __float2bfloat16(f);
            v[j] = *reinterpret_cast<ushort*>(&h);
        }
        *(ushort4v*)&dst[hh*XW + c0] = v;
    }
}

// ---------- MFMA conv + BN stats + horizontal 3x1 s2 pool, 7 ROWS PER WAVE ----------
// 512 blocks = EXACTLY 2 blocks/CU; bt staged once per block (o~5.6 amortized over
// 56 tiles); zero-weight k-groups 21..23 (ks=5, q>=1) zeroed in-register, not loaded.
__global__ __launch_bounds__(256)
void conv_mfma(const ushort* __restrict__ xp, const ushort* __restrict__ wt,
               ushort* __restrict__ yh, float* __restrict__ stats)
{
    __shared__ ushort bt[COUT*BROW];     // 25.6 KB
    __shared__ float red[4][2][COUT];    // 2 KB

    int bloc = blockIdx.x / 64;
    int rem  = blockIdx.x % 64;
    int tid  = threadIdx.x;
    int wid  = tid >> 6;
    int lane = tid & 63;
    int l15  = lane & 15;
    int q    = lane >> 4;
    int base = rem*28;                   // block covers rows [base, base+28)
    int b    = bloc;

    {   // stage wt row-block into LDS (coalesced dword copy, once per block)
        const uint* s = (const uint*)(wt + (size_t)b*COUT*BROW);
        uint* d = (uint*)bt;
        for (int i = tid; i < COUT*BROW/2; i += 256) d[i] = s[i];
    }
    __syncthreads();

    int goff[6];
    bool ld5 = (q == 0);                 // ks=5: g=20+q; g>=21 has zero weights
    #pragma unroll
    for (int ks = 0; ks < 6; ++ks) {
        int g = ks*4 + q;
        int gc = (g > 20) ? 20 : g;      // clamp (unused lanes), stay in-plane
        int ci = gc / 7, kh = gc - 7*ci;
        goff[ks] = (ci*XH + kh) * (XW*2);
    }

    float ss[4] = {0.f,0.f,0.f,0.f}, sq[4] = {0.f,0.f,0.f,0.f};

    #pragma unroll 1
    for (int t = 0; t < 7; ++t) {
        int row = base + wid + 4*t;      // 0..1791
        int n   = row / OHH;
        int oh  = row % OHH;
        int img = n*NBR + b;

        const char* rowbase = (const char*)xp + (size_t)img*(XIMG*2)
                            + (size_t)(2*oh)*(XW*2) + (size_t)(4*l15) - 4;
        ushort* yrow = yh + (size_t)bloc*YHSLOT + (((size_t)n*OHH + oh)*PWW)*64;

        #pragma unroll 1
        for (int u = 0; u < 8; ++u) {
            const char* abase = rowbase + (size_t)(56*u);

            uint4v afr[6];
            #pragma unroll
            for (int ks = 0; ks < 5; ++ks)
                __builtin_memcpy(&afr[ks], abase + goff[ks], 16);
            afr[5] = (uint4v){0u,0u,0u,0u};
            if (ld5) __builtin_memcpy(&afr[5], abase + goff[5], 16);

            f32x4 acc[4];
            #pragma unroll
            for (int nt = 0; nt < 4; ++nt) acc[nt] = (f32x4){0.f,0.f,0.f,0.f};

            #pragma unroll
            for (int ks = 0; ks < 6; ++ks)
                #pragma unroll
                for (int nt = 0; nt < 4; ++nt) {
                    uint4v bf = *(const uint4v*)&bt[(nt*16 + l15)*BROW + ks*32 + q*8];
                    acc[nt] = __builtin_amdgcn_mfma_f32_16x16x32_bf16(
                        __builtin_bit_cast(bf16x8, afr[ks]),
                        __builtin_bit_cast(bf16x8, bf), acc[nt], 0, 0, 0);
                }

            #pragma unroll
            for (int nt = 0; nt < 4; ++nt) {
                float v0 = acc[nt][0], v1 = acc[nt][1], v2 = acc[nt][2], v3 = acc[nt][3];

                // stats: locals 1..14 (q0 skips r0; q3 skips r3)
                float a0 = (q == 0) ? 0.f : v0;
                float a3 = (q == 3) ? 0.f : v3;
                ss[nt] += a0 + v1 + v2 + a3;
                sq[nt] += a0*a0 + v1*v1 + v2*v2 + a3*a3;

                float nv0 = __shfl_down(v0, 16);              // (q+1)'s v0
                float v0e = (u == 0 && q == 0) ? -3e38f : v0; // pw=0 left pad = -inf
                float m0 = fmaxf(fmaxf(v0e, v1), v2);         // pw = 7u + 2q
                float m1 = fmaxf(fmaxf(v2, v3), nv0);         // pw = 7u + 2q+1 (q<3)

                int o0 = (7*u + 2*q)*64 + nt*16 + l15;
                __hip_bfloat16 h0 = __float2bfloat16(m0);
                yrow[o0] = *reinterpret_cast<ushort*>(&h0);
                if (q < 3) {
                    __hip_bfloat16 h1 = __float2bfloat16(m1);
                    yrow[o0 + 64] = *reinterpret_cast<ushort*>(&h1);
                }
            }
        }
    }

    // stats: reduce over q lanes, then waves, one atomic per co
    #pragma unroll
    for (int nt = 0; nt < 4; ++nt) {
        float s1 = ss[nt]; s1 += __shfl_xor(s1, 16); s1 += __shfl_xor(s1, 32);
        float q1 = sq[nt]; q1 += __shfl_xor(q1, 16); q1 += __shfl_xor(q1, 32);
        if (q == 0) {
            red[wid][0][nt*16 + l15] = s1;
            red[wid][1][nt*16 + l15] = q1;
        }
    }
    __syncthreads();
    if (tid < COUT) {
        float s1 = red[0][0][tid] + red[1][0][tid] + red[2][0][tid] + red[3][0][tid];
        float q1 = red[0][1][tid] + red[1][1][tid] + red[2][1][tid] + red[3][1][tid];
        atomicAdd(&stats[b*128 + tid*2 + 0], s1);
        atomicAdd(&stats[b*128 + tid*2 + 1], q1);
    }
}

// ---------- vertical 3-tap pool + BN-affine + ReLU, NCHW write; 4 ph per block ----------
// res[PWW][65]: odd stride => conflict-free on both LDS phases (r20-proven).
__global__ __launch_bounds__(256)
void vpool(const ushort* __restrict__ yh, const float* __restrict__ stats,
           const float* __restrict__ gamma, const float* __restrict__ beta,
           float* __restrict__ out)
{
    int bid  = blockIdx.x;
    int bloc = bid / (NBATCH*(PHH/4));
    int r    = bid % (NBATCH*(PHH/4));
    int n    = r / (PHH/4);
    int phg  = r % (PHH/4);
    int b    = bloc;
    int tid  = threadIdx.x;

    __shared__ float res[PWW][COUT+1];
    __shared__ float sscale[COUT], sshift[COUT];

    if (tid < COUT) {
        float mean = stats[b*128 + tid*2 + 0] * (1.f/CNT);
        float var  = stats[b*128 + tid*2 + 1] * (1.f/CNT) - mean*mean;
        float inv  = rsqrtf(var + 1e-5f);
        float sc   = gamma[b*COUT + tid]*inv;
        sscale[tid] = sc;
        sshift[tid] = beta[b*COUT + tid] - mean*sc;
    }
    __syncthreads();

    const ushort* base = yh + (size_t)bloc*YHSLOT + (size_t)n*OHH*PWW*64;
    int c8 = (tid & 7) * 8;
    int pg = tid >> 3;           // 0..31

    #pragma unroll 1
    for (int pi = 0; pi < 4; ++pi) {
        int ph = phg*4 + pi;
        int ihA = (2*ph-1 < 0) ? 0 : 2*ph-1;
        int ihC = (2*ph+1 > OHH-1) ? OHH-1 : 2*ph+1;
        const ushort* rA = base + (size_t)ihA*PWW*64;
        const ushort* rB = base + (size_t)(2*ph)*PWW*64;
        const ushort* rC = base + (size_t)ihC*PWW*64;

        #pragma unroll
        for (int t = 0; t < 2; ++t) {
            int pw = pg + 32*t;
            if (pw < PWW) {
                int o = pw*64 + c8;
                uint4v a = *(const uint4v*)(rA + o);
                uint4v bb = *(const uint4v*)(rB + o);
                uint4v c = *(const uint4v*)(rC + o);
                #pragma unroll
                for (int i = 0; i < 4; ++i) {
                    uint ua = a[i], ub = bb[i], uc = c[i];
                    float a0 = __builtin_bit_cast(float, ua << 16);
                    float a1 = __builtin_bit_cast(float, ua & 0xffff0000u);
                    float b0 = __builtin_bit_cast(float, ub << 16);
                    float b1 = __builtin_bit_cast(float, ub & 0xffff0000u);
                    float c0 = __builtin_bit_cast(float, uc << 16);
                    float c1 = __builtin_bit_cast(float, uc & 0xffff0000u);
                    float m0 = fmaxf(fmaxf(a0, b0), c0);
                    float m1 = fmaxf(fmaxf(a1, b1), c1);
                    int co0 = c8 + 2*i, co1 = co0 + 1;
                    res[pw][co0] = fmaxf(fmaf(m0, sscale[co0], sshift[co0]), 0.f);
                    res[pw][co1] = fmaxf(fmaf(m1, sscale[co1], sshift[co1]), 0.f);
                }
            }
        }
        __syncthreads();

        float* ob = out + (((size_t)n*NBR + b)*COUT)*(PHH*PWW) + (size_t)ph*PWW;
        for (int j = tid; j < COUT*PWW; j += 256) {
            int co = j / PWW;
            int pw = j - co*PWW;
            ob[(size_t)co*(PHH*PWW) + pw] = res[pw][co];
        }
        __syncthreads();
    }
}

// ================= fallback path (tiny workspace) =================
__global__ __launch_bounds__(512)
void conv_bn_stats(const float* __restrict__ x, const float* __restrict__ w,
                   float* __restrict__ stats, int b)
{
    __shared__ float xs[CIN][7][232];
    int bid = blockIdx.x;
    int oh  = bid % OHH;
    int n   = bid / OHH;
    const float* xb = x + ((size_t)(n*NBR + b))*CIN*HIN*WIN;
    int ihb = oh*2 - 3;
    for (int idx = threadIdx.x; idx < CIN*7*230; idx += 512) {
        int ci = idx / (7*230);
        int rr = idx - ci*(7*230);
        int kh = rr / 230;
        int c  = rr - kh*230;
        int ih = ihb + kh, iw = c - 3;
        float v = 0.f;
        if ((unsigned)ih < (unsigned)HIN && (unsigned)iw < (unsigned)WIN)
            v = xb[(ci*HIN + ih)*WIN + iw];
        xs[ci][kh][c] = v;
    }
    __syncthreads();
    int wid  = __builtin_amdgcn_readfirstlane(threadIdx.x >> 6);
    int lane = threadIdx.x & 63;
    int co0  = wid * 8;
    const float* wb = w + ((size_t)b*COUT + co0)*147;
    float acc0[8], acc1[8];
    #pragma unroll
    for (int cc = 0; cc < 8; ++cc) { acc0[cc] = 0.f; acc1[cc] = 0.f; }
    int ow1 = lane + 64;
    for (int ci = 0; ci < CIN; ++ci)
        for (int kh = 0; kh < 7; ++kh) {
            float wr[8][7];
            #pragma unroll
            for (int cc = 0; cc < 8; ++cc)
                #pragma unroll
                for (int kw = 0; kw < 7; ++kw)
                    wr[cc][kw] = wb[cc*147 + ci*49 + kh*7 + kw];
            const float* xr = &xs[ci][kh][0];
            #pragma unroll
            for (int kw = 0; kw < 7; ++kw) {
                float xv0 = xr[lane*2 + kw];
                float xv1 = (ow1 < OWW) ? xr[ow1*2 + kw] : 0.f;
                #pragma unroll
                for (int cc = 0; cc < 8; ++cc) {
                    acc0[cc] = fmaf(xv0, wr[cc][kw], acc0[cc]);
                    acc1[cc] = fmaf(xv1, wr[cc][kw], acc1[cc]);
                }
            }
        }
    #pragma unroll
    for (int cc = 0; cc < 8; ++cc) {
        float s = acc0[cc] + acc1[cc];
        float qv = acc0[cc]*acc0[cc] + acc1[cc]*acc1[cc];
        #pragma unroll
        for (int off = 32; off; off >>= 1) {
            s  += __shfl_xor(s, off);
            qv += __shfl_xor(qv, off);
        }
        if (lane == 0) {
            atomicAdd(&stats[(co0+cc)*2 + 0], s);
            atomicAdd(&stats[(co0+cc)*2 + 1], qv);
        }
    }
}

__global__ __launch_bounds__(256)
void pool_recompute(const float* __restrict__ x, const float* __restrict__ w,
                    const float* __restrict__ stats, const float* __restrict__ gamma,
                    const float* __restrict__ beta, float* __restrict__ out, int b)
{
    int idx = blockIdx.x*256 + threadIdx.x;
    int pw = idx % PWW;
    int t  = idx / PWW;
    int ph = t % PHH; t /= PHH;
    int co = t % COUT;
    int n  = t / COUT;
    float mean = stats[co*2 + 0] * (1.f/CNT);
    float var  = stats[co*2 + 1] * (1.f/CNT) - mean*mean;
    float inv  = rsqrtf(var + 1e-5f);
    float scale = gamma[co]*inv;
    float shift = beta[co] - mean*scale;
    const float* xb = x + ((size_t)(n*NBR + b))*CIN*HIN*WIN;
    const float* wb = w + ((size_t)b*COUT + co)*147;
    float mx = -1e30f, mn = 1e30f;
    for (int dh = 0; dh < 3; ++dh) {
        int oh = 2*ph - 1 + dh;
        if ((unsigned)oh >= (unsigned)OHH) continue;
        for (int dw = 0; dw < 3; ++dw) {
            int ow = 2*pw - 1 + dw;
            if ((unsigned)ow >= (unsigned)OWW) continue;
            float a = 0.f;
            for (int ci = 0; ci < CIN; ++ci)
                for (int kh = 0; kh < 7; ++kh) {
                    int ih = oh*2 - 3 + kh;
                    if ((unsigned)ih >= (unsigned)HIN) continue;
                    for (int kw = 0; kw < 7; ++kw) {
                        int iw = ow*2 - 3 + kw;
                        if ((unsigned)iw >= (unsigned)WIN) continue;
                        a = fmaf(xb[(ci*HIN + ih)*WIN + iw], wb[ci*49 + kh*7 + kw], a);
                    }
                }
            mx = fmaxf(mx, a);
            mn = fminf(mn, a);
        }
    }
    float v = (scale >= 0.f) ? mx : mn;
    out[(((size_t)n*NBR + b)*COUT + co)*(PHH*PWW) + (size_t)ph*PWW + pw] =
        fmaxf(fmaf(v, scale, shift), 0.f);
}

extern "C" void kernel_launch(void* const* d_in, const int* in_sizes, int n_in,
                              void* d_out, int out_size, void* d_ws, size_t ws_size,
                              hipStream_t stream) {
    const float* x     = (const float*)d_in[0];
    const float* w     = (const float*)d_in[1];
    const float* gamma = (const float*)d_in[2];
    const float* beta  = (const float*)d_in[3];
    float* out = (float*)d_out;

    // ws: [0,4K) stats; [4K,~414K) wt; [512K, +41MB) xpad; then yh (102.8 MB)
    float*  stats = (float*)d_ws;
    ushort* wt    = (ushort*)((char*)d_ws + 4096);
    ushort* xp    = (ushort*)((char*)d_ws + 524288);
    const size_t xpend = 524288 + (size_t)128*XIMG*2;     // ~41.5 MB
    ushort* yh = (ushort*)((char*)d_ws + xpend);
    const size_t need = xpend + (size_t)NBR*YHSLOT*2;     // ~144 MB

    hipMemsetAsync(d_ws, 0, NBR*128*sizeof(float), stream);   // stats only

    if (ws_size >= need) {
        prep_w<<<(NBR*COUT*BROW + 255)/256, 256, 0, stream>>>(w, wt);
        prep_x<<<128*3*23, 256, 0, stream>>>(x, xp);
        conv_mfma<<<NBR*64, 256, 0, stream>>>(xp, wt, yh, stats);
        vpool<<<NBR*NBATCH*(PHH/4), 256, 0, stream>>>(yh, stats, gamma, beta, out);
    } else {
        for (int b = 0; b < NBR; ++b) {
            float* statsB = stats + b*128;
            conv_bn_stats<<<NBATCH*OHH, 512, 0, stream>>>(x, w, statsB, b);
            pool_recompute<<<NBATCH*COUT*PHH*PWW/256, 256, 0, stream>>>(
                x, w, statsB, gamma + b*COUT, beta + b*COUT, out, b);
        }
    }
}